// Round 1
// baseline (245.282 us; speedup 1.0000x reference)
//
#include <hip/hip_runtime.h>
#include <stdint.h>

#define D_MODEL 1024
#define T_LEN   4096
#define B_SZ    4
#define NROWS   (B_SZ * T_LEN)   // 16384
#define NPROJ   (2 * D_MODEL)    // 2048

typedef __attribute__((ext_vector_type(8))) __bf16 bf16x8;
typedef __attribute__((ext_vector_type(4))) float  f32x4;

using as1_void = __attribute__((address_space(1))) void;
using as3_void = __attribute__((address_space(3))) void;

__device__ inline float bf2f(unsigned short u) {
    union { unsigned int i; float f; } v; v.i = ((unsigned int)u) << 16; return v.f;
}
__device__ inline unsigned short f2bf(float f) {
    union { float f; unsigned int i; } v; v.f = f;
    return (unsigned short)((v.i + 0x7fffu + ((v.i >> 16) & 1u)) >> 16);
}
__device__ inline float sigmoidf(float x) { return 1.0f / (1.0f + __expf(-x)); }

// ---------------- K0a: x fp32 -> bf16 ----------------
__global__ __launch_bounds__(256) void k_cvt_x(const float* __restrict__ x,
                                               unsigned short* __restrict__ xb) {
    int i = (blockIdx.x * 256 + threadIdx.x) * 4;
    float4 v = *reinterpret_cast<const float4*>(x + i);
    ushort4 o;
    o.x = f2bf(v.x); o.y = f2bf(v.y); o.z = f2bf(v.z); o.w = f2bf(v.w);
    *reinterpret_cast<ushort4*>(xb + i) = o;
}

// ---------------- K0b: W (1024x2048) -> W^T (2048x1024) bf16 ----------------
__global__ __launch_bounds__(256) void k_cvt_w(const float* __restrict__ W,
                                               unsigned short* __restrict__ wt) {
    __shared__ unsigned short tile[32][33];
    int n0 = blockIdx.x * 32, k0 = blockIdx.y * 32;
    int c = threadIdx.x & 31, r = threadIdx.x >> 5;  // r in 0..7
    #pragma unroll
    for (int i = 0; i < 4; i++) {
        int kk = r + i * 8;
        tile[kk][c] = f2bf(W[(uint64_t)(k0 + kk) * NPROJ + n0 + c]);
    }
    __syncthreads();
    #pragma unroll
    for (int i = 0; i < 4; i++) {
        int nn = r + i * 8;
        wt[(uint64_t)(n0 + nn) * D_MODEL + k0 + c] = tile[c][nn];
    }
}

// ---------------- K1: GEMM proj = xb @ wt^T + bias, store bf16 ----------------
// A: xb (16384 x 1024) bf16 row-major; B: wt (2048 x 1024) bf16 (i.e., W^T, n-major)
// Tile 128x128, BK=64, 4 waves (2x2), each wave 64x64 = 4x4 fragments of 16x16x32.
__global__ __launch_bounds__(256) void k_gemm(const unsigned short* __restrict__ xb,
                                              const unsigned short* __restrict__ wt,
                                              const float* __restrict__ bias,
                                              unsigned short* __restrict__ projb) {
    __shared__ __align__(16) unsigned short As[128 * 64];
    __shared__ __align__(16) unsigned short Bs[128 * 64];

    const int tid  = threadIdx.x;
    const int lane = tid & 63;
    const int w    = tid >> 6;       // wave 0..3
    const int wm   = w >> 1, wn = w & 1;
    const int m0   = blockIdx.y * 128;
    const int n0   = blockIdx.x * 128;

    const int lrow = lane >> 3;        // 0..7
    const int lcol = (lane & 7) * 8;   // 0,8,..,56 (bf16 elements)
    const int fr   = lane & 15;
    const int fq   = lane >> 4;        // 0..3

    f32x4 acc[4][4] = {};

    for (int ks = 0; ks < D_MODEL; ks += 64) {
        // stage A tile: 16KB via 16 global_load_lds chunks of 1KB
        #pragma unroll
        for (int s = 0; s < 4; ++s) {
            const int chunk = w * 4 + s;           // 0..15 (wave-uniform)
            const int row   = chunk * 8 + lrow;    // 0..127
            const unsigned short* g = xb + (uint64_t)(m0 + row) * D_MODEL + ks + lcol;
            __builtin_amdgcn_global_load_lds((as1_void*)(void*)g,
                                             (as3_void*)(void*)&As[chunk * 512],
                                             16, 0, 0);
        }
        // stage B tile
        #pragma unroll
        for (int s = 0; s < 4; ++s) {
            const int chunk = w * 4 + s;
            const int row   = chunk * 8 + lrow;
            const unsigned short* g = wt + (uint64_t)(n0 + row) * D_MODEL + ks + lcol;
            __builtin_amdgcn_global_load_lds((as1_void*)(void*)g,
                                             (as3_void*)(void*)&Bs[chunk * 512],
                                             16, 0, 0);
        }
        __syncthreads();

        #pragma unroll
        for (int kk = 0; kk < 64; kk += 32) {
            bf16x8 a[4], b[4];
            #pragma unroll
            for (int m = 0; m < 4; m++)
                a[m] = *reinterpret_cast<const bf16x8*>(&As[(wm * 64 + m * 16 + fr) * 64 + kk + fq * 8]);
            #pragma unroll
            for (int n = 0; n < 4; n++)
                b[n] = *reinterpret_cast<const bf16x8*>(&Bs[(wn * 64 + n * 16 + fr) * 64 + kk + fq * 8]);
            #pragma unroll
            for (int m = 0; m < 4; m++)
                #pragma unroll
                for (int n = 0; n < 4; n++)
                    acc[m][n] = __builtin_amdgcn_mfma_f32_16x16x32_bf16(a[m], b[n], acc[m][n], 0, 0, 0);
        }
        __syncthreads();
    }

    // epilogue: D layout col=lane&15, row=(lane>>4)*4+reg  [verified m89/m91]
    #pragma unroll
    for (int m = 0; m < 4; m++) {
        const int grow_base = m0 + wm * 64 + m * 16 + fq * 4;
        #pragma unroll
        for (int n = 0; n < 4; n++) {
            const int gcol = n0 + wn * 64 + n * 16 + fr;
            const float bv = bias[gcol];
            #pragma unroll
            for (int r = 0; r < 4; r++) {
                projb[(uint64_t)(grow_base + r) * NPROJ + gcol] = f2bf(acc[m][n][r] + bv);
            }
        }
    }
}

// ---------------- K2: RoPE + depthwise conv7 + SiLU + gate + RMSNorm ----------------
// one block per (b,t) row; 256 threads x 4 channels each
__global__ __launch_bounds__(256) void k_post(const unsigned short* __restrict__ projb,
                                              const float* __restrict__ sinp,
                                              const float* __restrict__ cosp,
                                              const float* __restrict__ kw,
                                              const float* __restrict__ dwb,
                                              const float* __restrict__ gamma,
                                              float* __restrict__ out) {
    const int row = blockIdx.x;            // b*T + t
    const int t   = row & (T_LEN - 1);
    const int tid = threadIdx.x;
    const int d0  = tid * 4;
    const int h0  = d0 >> 1;               // rope pair index (even)

    float acc0 = 0.f, acc1 = 0.f, acc2 = 0.f, acc3 = 0.f;
    #pragma unroll
    for (int j = 0; j < 7; j++) {
        const int tj = t + j - 3;
        if (tj < 0 || tj >= T_LEN) continue;
        const int rj = row + j - 3;
        ushort4 u = *reinterpret_cast<const ushort4*>(projb + (uint64_t)rj * NPROJ + d0);
        float x0 = bf2f(u.x), x1 = bf2f(u.y), x2 = bf2f(u.z), x3 = bf2f(u.w);
        float2 cc = *reinterpret_cast<const float2*>(cosp + (uint64_t)tj * (D_MODEL / 2) + h0);
        float2 ss = *reinterpret_cast<const float2*>(sinp + (uint64_t)tj * (D_MODEL / 2) + h0);
        float r0 = x0 * cc.x - x1 * ss.x;
        float r1 = x0 * ss.x + x1 * cc.x;
        float r2 = x2 * cc.y - x3 * ss.y;
        float r3 = x2 * ss.y + x3 * cc.y;
        float4 k4 = *reinterpret_cast<const float4*>(kw + j * D_MODEL + d0);
        acc0 += r0 * k4.x; acc1 += r1 * k4.y; acc2 += r2 * k4.z; acc3 += r3 * k4.w;
    }
    float4 bv = *reinterpret_cast<const float4*>(dwb + d0);
    acc0 += bv.x; acc1 += bv.y; acc2 += bv.z; acc3 += bv.w;

    // SiLU(conv)
    float a0 = acc0 * sigmoidf(acc0);
    float a1 = acc1 * sigmoidf(acc1);
    float a2 = acc2 * sigmoidf(acc2);
    float a3 = acc3 * sigmoidf(acc3);

    // gate by sigmoid(x_b)
    ushort4 ub = *reinterpret_cast<const ushort4*>(projb + (uint64_t)row * NPROJ + D_MODEL + d0);
    float g0 = a0 * sigmoidf(bf2f(ub.x));
    float g1 = a1 * sigmoidf(bf2f(ub.y));
    float g2 = a2 * sigmoidf(bf2f(ub.z));
    float g3 = a3 * sigmoidf(bf2f(ub.w));

    // RMS over D=1024
    float ssq = g0 * g0 + g1 * g1 + g2 * g2 + g3 * g3;
    #pragma unroll
    for (int off = 32; off; off >>= 1) ssq += __shfl_down(ssq, off);
    __shared__ float red[4];
    if ((tid & 63) == 0) red[tid >> 6] = ssq;
    __syncthreads();
    const float total = red[0] + red[1] + red[2] + red[3];
    const float inv = 1.0f / sqrtf(total * (1.0f / (float)D_MODEL) + 1e-8f);

    float4 gm = *reinterpret_cast<const float4*>(gamma + d0);
    float4 o;
    o.x = g0 * inv * gm.x; o.y = g1 * inv * gm.y;
    o.z = g2 * inv * gm.z; o.w = g3 * inv * gm.w;
    *reinterpret_cast<float4*>(out + (uint64_t)row * D_MODEL + d0) = o;
}

extern "C" void kernel_launch(void* const* d_in, const int* in_sizes, int n_in,
                              void* d_out, int out_size, void* d_ws, size_t ws_size,
                              hipStream_t stream) {
    const float* x     = (const float*)d_in[0];
    const float* sinp  = (const float*)d_in[1];
    const float* cosp  = (const float*)d_in[2];
    const float* W     = (const float*)d_in[3];
    const float* bproj = (const float*)d_in[4];
    const float* dwk   = (const float*)d_in[5];
    const float* dwb   = (const float*)d_in[6];
    const float* gamma = (const float*)d_in[7];
    float* out = (float*)d_out;

    unsigned short* xb    = (unsigned short*)d_ws;                       // 32 MB
    unsigned short* wt    = xb + (size_t)NROWS * D_MODEL;                // 4 MB
    unsigned short* projb = wt + (size_t)NPROJ * D_MODEL;                // 64 MB

    k_cvt_x<<<(NROWS * D_MODEL) / (256 * 4), 256, 0, stream>>>(x, xb);
    k_cvt_w<<<dim3(NPROJ / 32, D_MODEL / 32), 256, 0, stream>>>(W, wt);
    k_gemm<<<dim3(NPROJ / 128, NROWS / 128), 256, 0, stream>>>(xb, wt, bproj, projb);
    k_post<<<NROWS, 256, 0, stream>>>(projb, sinp, cosp, dwk, dwb, gamma, out);
}

// Round 2
// 174.838 us; speedup vs baseline: 1.4029x; 1.4029x over previous
//
#include <hip/hip_runtime.h>
#include <stdint.h>

#define D_MODEL 1024
#define T_LEN   4096
#define B_SZ    4
#define NROWS   (B_SZ * T_LEN)   // 16384
#define NPROJ   (2 * D_MODEL)    // 2048
#define CHUNK   16               // rows of T per k_post block

typedef __attribute__((ext_vector_type(8))) __bf16 bf16x8;
typedef __attribute__((ext_vector_type(4))) float  f32x4;

using as1_void = __attribute__((address_space(1))) void;
using as3_void = __attribute__((address_space(3))) void;

__device__ inline float bf2f(unsigned short u) {
    union { unsigned int i; float f; } v; v.i = ((unsigned int)u) << 16; return v.f;
}
__device__ inline unsigned short f2bf(float f) {
    union { float f; unsigned int i; } v; v.f = f;
    return (unsigned short)((v.i + 0x7fffu + ((v.i >> 16) & 1u)) >> 16);
}
__device__ inline float sigmoidf(float x) { return 1.0f / (1.0f + __expf(-x)); }

// ---------------- K0a: x fp32 -> bf16 ----------------
__global__ __launch_bounds__(256) void k_cvt_x(const float* __restrict__ x,
                                               unsigned short* __restrict__ xb) {
    int i = (blockIdx.x * 256 + threadIdx.x) * 4;
    float4 v = *reinterpret_cast<const float4*>(x + i);
    ushort4 o;
    o.x = f2bf(v.x); o.y = f2bf(v.y); o.z = f2bf(v.z); o.w = f2bf(v.w);
    *reinterpret_cast<ushort4*>(xb + i) = o;
}

// ---------------- K0b: W (1024x2048) -> W^T (2048x1024) bf16 ----------------
__global__ __launch_bounds__(256) void k_cvt_w(const float* __restrict__ W,
                                               unsigned short* __restrict__ wt) {
    __shared__ unsigned short tile[32][33];
    int n0 = blockIdx.x * 32, k0 = blockIdx.y * 32;
    int c = threadIdx.x & 31, r = threadIdx.x >> 5;  // r in 0..7
    #pragma unroll
    for (int i = 0; i < 4; i++) {
        int kk = r + i * 8;
        tile[kk][c] = f2bf(W[(uint64_t)(k0 + kk) * NPROJ + n0 + c]);
    }
    __syncthreads();
    #pragma unroll
    for (int i = 0; i < 4; i++) {
        int nn = r + i * 8;
        wt[(uint64_t)(n0 + nn) * D_MODEL + k0 + c] = tile[c][nn];
    }
}

// ---------------- K1: GEMM proj = xb @ wt^T + bias, store bf16 ----------------
__global__ __launch_bounds__(256) void k_gemm(const unsigned short* __restrict__ xb,
                                              const unsigned short* __restrict__ wt,
                                              const float* __restrict__ bias,
                                              unsigned short* __restrict__ projb) {
    __shared__ __align__(16) unsigned short As[128 * 64];
    __shared__ __align__(16) unsigned short Bs[128 * 64];

    const int tid  = threadIdx.x;
    const int lane = tid & 63;
    const int w    = tid >> 6;       // wave 0..3
    const int wm   = w >> 1, wn = w & 1;
    const int m0   = blockIdx.y * 128;
    const int n0   = blockIdx.x * 128;

    const int lrow = lane >> 3;        // 0..7
    const int lcol = (lane & 7) * 8;   // 0,8,..,56 (bf16 elements)
    const int fr   = lane & 15;
    const int fq   = lane >> 4;        // 0..3

    f32x4 acc[4][4] = {};

    for (int ks = 0; ks < D_MODEL; ks += 64) {
        #pragma unroll
        for (int s = 0; s < 4; ++s) {
            const int chunk = w * 4 + s;           // 0..15 (wave-uniform)
            const int row   = chunk * 8 + lrow;    // 0..127
            const unsigned short* g = xb + (uint64_t)(m0 + row) * D_MODEL + ks + lcol;
            __builtin_amdgcn_global_load_lds((as1_void*)(void*)g,
                                             (as3_void*)(void*)&As[chunk * 512],
                                             16, 0, 0);
        }
        #pragma unroll
        for (int s = 0; s < 4; ++s) {
            const int chunk = w * 4 + s;
            const int row   = chunk * 8 + lrow;
            const unsigned short* g = wt + (uint64_t)(n0 + row) * D_MODEL + ks + lcol;
            __builtin_amdgcn_global_load_lds((as1_void*)(void*)g,
                                             (as3_void*)(void*)&Bs[chunk * 512],
                                             16, 0, 0);
        }
        __syncthreads();

        #pragma unroll
        for (int kk = 0; kk < 64; kk += 32) {
            bf16x8 a[4], b[4];
            #pragma unroll
            for (int m = 0; m < 4; m++)
                a[m] = *reinterpret_cast<const bf16x8*>(&As[(wm * 64 + m * 16 + fr) * 64 + kk + fq * 8]);
            #pragma unroll
            for (int n = 0; n < 4; n++)
                b[n] = *reinterpret_cast<const bf16x8*>(&Bs[(wn * 64 + n * 16 + fr) * 64 + kk + fq * 8]);
            #pragma unroll
            for (int m = 0; m < 4; m++)
                #pragma unroll
                for (int n = 0; n < 4; n++)
                    acc[m][n] = __builtin_amdgcn_mfma_f32_16x16x32_bf16(a[m], b[n], acc[m][n], 0, 0, 0);
        }
        __syncthreads();
    }

    // epilogue: D layout col=lane&15, row=(lane>>4)*4+reg  [verified m89/m91]
    #pragma unroll
    for (int m = 0; m < 4; m++) {
        const int grow_base = m0 + wm * 64 + m * 16 + fq * 4;
        #pragma unroll
        for (int n = 0; n < 4; n++) {
            const int gcol = n0 + wn * 64 + n * 16 + fr;
            const float bv = bias[gcol];
            #pragma unroll
            for (int r = 0; r < 4; r++) {
                projb[(uint64_t)(grow_base + r) * NPROJ + gcol] = f2bf(acc[m][n][r] + bv);
            }
        }
    }
}

// ---------------- K2: streaming RoPE + conv7 + SiLU + gate + RMSNorm ----------------
// 512 threads, each owns one RoPE pair (2 channels). One block per (batch, CHUNK of T).
// 7-tap register shift-ring, each projb/cos/sin row loaded once (+halo).
__global__ __launch_bounds__(512) void k_post(const unsigned short* __restrict__ projb,
                                              const float* __restrict__ sinp,
                                              const float* __restrict__ cosp,
                                              const float* __restrict__ kw,
                                              const float* __restrict__ dwb,
                                              const float* __restrict__ gamma,
                                              float* __restrict__ out) {
    const int blk  = blockIdx.x;
    const int b    = blk / (T_LEN / CHUNK);
    const int t0   = (blk % (T_LEN / CHUNK)) * CHUNK;
    const int c    = threadIdx.x;          // pair index 0..511
    const int d0   = c * 2;
    const uint64_t bbase = (uint64_t)b * T_LEN;

    // preload per-channel constants into registers
    float kwv[7][2];
    #pragma unroll
    for (int j = 0; j < 7; j++) {
        kwv[j][0] = kw[j * D_MODEL + d0];
        kwv[j][1] = kw[j * D_MODEL + d0 + 1];
    }
    const float bv0 = dwb[d0], bv1 = dwb[d0 + 1];
    const float gm0 = gamma[d0], gm1 = gamma[d0 + 1];

    __shared__ float red[2][8];

    // load + RoPE one tap row (tj); zero outside [0,T)
    auto load_rope = [&](int tj, float& o0, float& o1) {
        if ((unsigned)tj < (unsigned)T_LEN) {
            ushort2 u = *reinterpret_cast<const ushort2*>(projb + (bbase + tj) * NPROJ + d0);
            float cv = cosp[(uint64_t)tj * (D_MODEL / 2) + c];
            float sv = sinp[(uint64_t)tj * (D_MODEL / 2) + c];
            float x0 = bf2f(u.x), x1 = bf2f(u.y);
            o0 = x0 * cv - x1 * sv;
            o1 = x0 * sv + x1 * cv;
        } else { o0 = 0.f; o1 = 0.f; }
    };

    float rg[6][2];
    #pragma unroll
    for (int j = 0; j < 6; j++) load_rope(t0 - 3 + j, rg[j][0], rg[j][1]);
    float nx0, nx1;
    load_rope(t0 + 3, nx0, nx1);                 // tap for first row

    // prefetch first x_b row
    ushort2 xb_cur = *reinterpret_cast<const ushort2*>(projb + (bbase + t0) * NPROJ + D_MODEL + d0);

    for (int t = t0; t < t0 + CHUNK; ++t) {
        const float r60 = nx0, r61 = nx1;

        float acc0 = rg[0][0] * kwv[0][0] + rg[1][0] * kwv[1][0] + rg[2][0] * kwv[2][0]
                   + rg[3][0] * kwv[3][0] + rg[4][0] * kwv[4][0] + rg[5][0] * kwv[5][0]
                   + r60 * kwv[6][0] + bv0;
        float acc1 = rg[0][1] * kwv[0][1] + rg[1][1] * kwv[1][1] + rg[2][1] * kwv[2][1]
                   + rg[3][1] * kwv[3][1] + rg[4][1] * kwv[4][1] + rg[5][1] * kwv[5][1]
                   + r61 * kwv[6][1] + bv1;

        // prefetch next tap + next x_b (hidden under reduce/store)
        load_rope(t + 4, nx0, nx1);
        const ushort2 xb_use = xb_cur;
        if (t + 1 < t0 + CHUNK) {
            xb_cur = *reinterpret_cast<const ushort2*>(projb + (bbase + t + 1) * NPROJ + D_MODEL + d0);
        }

        // SiLU + gate
        float a0 = acc0 * sigmoidf(acc0);
        float a1 = acc1 * sigmoidf(acc1);
        float g0 = a0 * sigmoidf(bf2f(xb_use.x));
        float g1 = a1 * sigmoidf(bf2f(xb_use.y));

        // RMS over D=1024 (512 threads x 2 ch)
        float ssq = g0 * g0 + g1 * g1;
        #pragma unroll
        for (int off = 32; off; off >>= 1) ssq += __shfl_down(ssq, off);
        const int p = t & 1;
        if ((threadIdx.x & 63) == 0) red[p][threadIdx.x >> 6] = ssq;
        __syncthreads();
        float total = red[p][0] + red[p][1] + red[p][2] + red[p][3]
                    + red[p][4] + red[p][5] + red[p][6] + red[p][7];
        const float inv = 1.0f / sqrtf(total * (1.0f / (float)D_MODEL) + 1e-8f);

        float2 o;
        o.x = g0 * inv * gm0;
        o.y = g1 * inv * gm1;
        *reinterpret_cast<float2*>(out + (bbase + t) * D_MODEL + d0) = o;

        // shift ring (static indices)
        #pragma unroll
        for (int j = 0; j < 5; j++) { rg[j][0] = rg[j + 1][0]; rg[j][1] = rg[j + 1][1]; }
        rg[5][0] = r60; rg[5][1] = r61;
    }
}

extern "C" void kernel_launch(void* const* d_in, const int* in_sizes, int n_in,
                              void* d_out, int out_size, void* d_ws, size_t ws_size,
                              hipStream_t stream) {
    const float* x     = (const float*)d_in[0];
    const float* sinp  = (const float*)d_in[1];
    const float* cosp  = (const float*)d_in[2];
    const float* W     = (const float*)d_in[3];
    const float* bproj = (const float*)d_in[4];
    const float* dwk   = (const float*)d_in[5];
    const float* dwb   = (const float*)d_in[6];
    const float* gamma = (const float*)d_in[7];
    float* out = (float*)d_out;

    unsigned short* xb    = (unsigned short*)d_ws;                       // 32 MB
    unsigned short* wt    = xb + (size_t)NROWS * D_MODEL;                // 4 MB
    unsigned short* projb = wt + (size_t)NPROJ * D_MODEL;                // 64 MB

    k_cvt_x<<<(NROWS * D_MODEL) / (256 * 4), 256, 0, stream>>>(x, xb);
    k_cvt_w<<<dim3(NPROJ / 32, D_MODEL / 32), 256, 0, stream>>>(W, wt);
    k_gemm<<<dim3(NPROJ / 128, NROWS / 128), 256, 0, stream>>>(xb, wt, bproj, projb);
    k_post<<<B_SZ * (T_LEN / CHUNK), 512, 0, stream>>>(projb, sinp, cosp, dwk, dwb, gamma, out);
}

// Round 3
// 148.972 us; speedup vs baseline: 1.6465x; 1.1736x over previous
//
#include <hip/hip_runtime.h>
#include <stdint.h>

#define D_MODEL 1024
#define T_LEN   4096
#define B_SZ    4
#define NROWS   (B_SZ * T_LEN)   // 16384
#define NPROJ   (2 * D_MODEL)    // 2048
#define CHUNK   16               // rows of T per k_post block

#define BM 256
#define BN 256
#define BK 64
#define NT (D_MODEL / BK)        // 16 K-steps

typedef __attribute__((ext_vector_type(8))) __bf16 bf16x8;
typedef __attribute__((ext_vector_type(4))) float  f32x4;

using as1_void = __attribute__((address_space(1))) void;
using as3_void = __attribute__((address_space(3))) void;

__device__ inline float bf2f(unsigned short u) {
    union { unsigned int i; float f; } v; v.i = ((unsigned int)u) << 16; return v.f;
}
__device__ inline unsigned short f2bf(float f) {
    union { float f; unsigned int i; } v; v.f = f;
    return (unsigned short)((v.i + 0x7fffu + ((v.i >> 16) & 1u)) >> 16);
}
__device__ inline float sigmoidf(float x) { return 1.0f / (1.0f + __expf(-x)); }

// ---------------- K0a: x fp32 -> bf16 ----------------
__global__ __launch_bounds__(256) void k_cvt_x(const float* __restrict__ x,
                                               unsigned short* __restrict__ xb) {
    int i = (blockIdx.x * 256 + threadIdx.x) * 4;
    float4 v = *reinterpret_cast<const float4*>(x + i);
    ushort4 o;
    o.x = f2bf(v.x); o.y = f2bf(v.y); o.z = f2bf(v.z); o.w = f2bf(v.w);
    *reinterpret_cast<ushort4*>(xb + i) = o;
}

// ---------------- K0b: W (1024x2048) -> W^T (2048x1024) bf16 ----------------
__global__ __launch_bounds__(256) void k_cvt_w(const float* __restrict__ W,
                                               unsigned short* __restrict__ wt) {
    __shared__ unsigned short tile[32][33];
    int n0 = blockIdx.x * 32, k0 = blockIdx.y * 32;
    int c = threadIdx.x & 31, r = threadIdx.x >> 5;  // r in 0..7
    #pragma unroll
    for (int i = 0; i < 4; i++) {
        int kk = r + i * 8;
        tile[kk][c] = f2bf(W[(uint64_t)(k0 + kk) * NPROJ + n0 + c]);
    }
    __syncthreads();
    #pragma unroll
    for (int i = 0; i < 4; i++) {
        int nn = r + i * 8;
        wt[(uint64_t)(n0 + nn) * D_MODEL + k0 + c] = tile[c][nn];
    }
}

// ---------------- K1: GEMM proj = xb @ wt^T + bias, store bf16 ----------------
// 256x256 tile, BK=64, 8 waves (2Mx4N), double-buffered LDS (128 KiB),
// issue-first staging (T3-min), st-xor LDS swizzle (T2, both-sides involution),
// XCD-aware block swizzle (T1: each XCD owns one n-column -> B-panel L2-resident).
__global__ __launch_bounds__(512, 2) void k_gemm(const unsigned short* __restrict__ xb,
                                                 const unsigned short* __restrict__ wt,
                                                 const float* __restrict__ bias,
                                                 unsigned short* __restrict__ projb) {
    __shared__ __align__(16) unsigned short As[2 * BM * BK];  // 64 KB
    __shared__ __align__(16) unsigned short Bs[2 * BM * BK];  // 64 KB

    const int tid  = threadIdx.x;
    const int lane = tid & 63;
    const int w    = tid >> 6;       // wave 0..7
    const int wm   = w >> 2;         // 0..1  (M half)
    const int wn   = w & 3;          // 0..3  (N quarter)

    // T1: 512 blocks = 8 n-tiles x 64 m-tiles; XCD k owns n-column k.
    const int bid = blockIdx.x;
    const int wg  = (bid & 7) * 64 + (bid >> 3);
    const int n0  = (wg >> 6) * BN;
    const int m0  = (wg & 63) * BM;

    // staging geometry: 512 threads x 16B = 8KB/issue; 4 issues per 32KB tile.
    const int srow = tid >> 3;                        // LDS row (mod 64) this thread fills
    const int scol = ((tid & 7) ^ (srow & 7)) * 8;    // T2: inverse-swizzled global col
    const int fr   = lane & 15;
    const int fq   = lane >> 4;

    f32x4 acc[8][4] = {};

    auto STAGE = [&](int buf, int ks) {
        #pragma unroll
        for (int i = 0; i < 4; ++i) {
            const unsigned short* ga = xb + (uint64_t)(m0 + i * 64 + srow) * D_MODEL + ks + scol;
            __builtin_amdgcn_global_load_lds((as1_void*)(void*)ga,
                (as3_void*)(void*)&As[buf * (BM * BK) + i * 4096 + w * 512], 16, 0, 0);
        }
        #pragma unroll
        for (int i = 0; i < 4; ++i) {
            const unsigned short* gb = wt + (uint64_t)(n0 + i * 64 + srow) * D_MODEL + ks + scol;
            __builtin_amdgcn_global_load_lds((as1_void*)(void*)gb,
                (as3_void*)(void*)&Bs[buf * (BM * BK) + i * 4096 + w * 512], 16, 0, 0);
        }
    };

    STAGE(0, 0);
    __syncthreads();

    for (int t = 0; t < NT; ++t) {
        const int cur = t & 1;
        if (t + 1 < NT) STAGE(1 - cur, (t + 1) * BK);   // issue-first prefetch

        const unsigned short* Ab = &As[cur * (BM * BK)];
        const unsigned short* Bb = &Bs[cur * (BM * BK)];
        #pragma unroll
        for (int kk = 0; kk < BK; kk += 32) {
            const int slot = (kk >> 3) + fq;            // global k-octet
            bf16x8 b[4];
            #pragma unroll
            for (int n = 0; n < 4; n++) {
                const int rb = wn * 64 + n * 16 + fr;
                b[n] = *reinterpret_cast<const bf16x8*>(&Bb[rb * 64 + ((slot ^ (fr & 7)) * 8)]);
            }
            #pragma unroll
            for (int m = 0; m < 8; m++) {
                const int ra = wm * 128 + m * 16 + fr;
                bf16x8 a = *reinterpret_cast<const bf16x8*>(&Ab[ra * 64 + ((slot ^ (fr & 7)) * 8)]);
                #pragma unroll
                for (int n = 0; n < 4; n++)
                    acc[m][n] = __builtin_amdgcn_mfma_f32_16x16x32_bf16(a, b[n], acc[m][n], 0, 0, 0);
            }
        }
        __syncthreads();   // drains vmcnt(0): next tile landed; LDS reads done
    }

    // epilogue: D layout col=lane&15, row=(lane>>4)*4+reg  [verified m89/m91]
    #pragma unroll
    for (int m = 0; m < 8; m++) {
        const int grow = m0 + wm * 128 + m * 16 + fq * 4;
        #pragma unroll
        for (int n = 0; n < 4; n++) {
            const int gcol = n0 + wn * 64 + n * 16 + fr;
            const float bv = bias[gcol];
            #pragma unroll
            for (int r = 0; r < 4; r++) {
                projb[(uint64_t)(grow + r) * NPROJ + gcol] = f2bf(acc[m][n][r] + bv);
            }
        }
    }
}

// ---------------- K2: streaming RoPE + conv7 + SiLU + gate + RMSNorm ----------------
__global__ __launch_bounds__(512) void k_post(const unsigned short* __restrict__ projb,
                                              const float* __restrict__ sinp,
                                              const float* __restrict__ cosp,
                                              const float* __restrict__ kw,
                                              const float* __restrict__ dwb,
                                              const float* __restrict__ gamma,
                                              float* __restrict__ out) {
    const int blk  = blockIdx.x;
    const int b    = blk / (T_LEN / CHUNK);
    const int t0   = (blk % (T_LEN / CHUNK)) * CHUNK;
    const int c    = threadIdx.x;          // pair index 0..511
    const int d0   = c * 2;
    const uint64_t bbase = (uint64_t)b * T_LEN;

    float kwv[7][2];
    #pragma unroll
    for (int j = 0; j < 7; j++) {
        kwv[j][0] = kw[j * D_MODEL + d0];
        kwv[j][1] = kw[j * D_MODEL + d0 + 1];
    }
    const float bv0 = dwb[d0], bv1 = dwb[d0 + 1];
    const float gm0 = gamma[d0], gm1 = gamma[d0 + 1];

    __shared__ float red[2][8];

    auto load_rope = [&](int tj, float& o0, float& o1) {
        if ((unsigned)tj < (unsigned)T_LEN) {
            ushort2 u = *reinterpret_cast<const ushort2*>(projb + (bbase + tj) * NPROJ + d0);
            float cv = cosp[(uint64_t)tj * (D_MODEL / 2) + c];
            float sv = sinp[(uint64_t)tj * (D_MODEL / 2) + c];
            float x0 = bf2f(u.x), x1 = bf2f(u.y);
            o0 = x0 * cv - x1 * sv;
            o1 = x0 * sv + x1 * cv;
        } else { o0 = 0.f; o1 = 0.f; }
    };

    float rg[6][2];
    #pragma unroll
    for (int j = 0; j < 6; j++) load_rope(t0 - 3 + j, rg[j][0], rg[j][1]);
    float nx0, nx1;
    load_rope(t0 + 3, nx0, nx1);

    ushort2 xb_cur = *reinterpret_cast<const ushort2*>(projb + (bbase + t0) * NPROJ + D_MODEL + d0);

    for (int t = t0; t < t0 + CHUNK; ++t) {
        const float r60 = nx0, r61 = nx1;

        float acc0 = rg[0][0] * kwv[0][0] + rg[1][0] * kwv[1][0] + rg[2][0] * kwv[2][0]
                   + rg[3][0] * kwv[3][0] + rg[4][0] * kwv[4][0] + rg[5][0] * kwv[5][0]
                   + r60 * kwv[6][0] + bv0;
        float acc1 = rg[0][1] * kwv[0][1] + rg[1][1] * kwv[1][1] + rg[2][1] * kwv[2][1]
                   + rg[3][1] * kwv[3][1] + rg[4][1] * kwv[4][1] + rg[5][1] * kwv[5][1]
                   + r61 * kwv[6][1] + bv1;

        load_rope(t + 4, nx0, nx1);
        const ushort2 xb_use = xb_cur;
        if (t + 1 < t0 + CHUNK) {
            xb_cur = *reinterpret_cast<const ushort2*>(projb + (bbase + t + 1) * NPROJ + D_MODEL + d0);
        }

        float a0 = acc0 * sigmoidf(acc0);
        float a1 = acc1 * sigmoidf(acc1);
        float g0 = a0 * sigmoidf(bf2f(xb_use.x));
        float g1 = a1 * sigmoidf(bf2f(xb_use.y));

        float ssq = g0 * g0 + g1 * g1;
        #pragma unroll
        for (int off = 32; off; off >>= 1) ssq += __shfl_down(ssq, off);
        const int p = t & 1;
        if ((threadIdx.x & 63) == 0) red[p][threadIdx.x >> 6] = ssq;
        __syncthreads();
        float total = red[p][0] + red[p][1] + red[p][2] + red[p][3]
                    + red[p][4] + red[p][5] + red[p][6] + red[p][7];
        const float inv = 1.0f / sqrtf(total * (1.0f / (float)D_MODEL) + 1e-8f);

        float2 o;
        o.x = g0 * inv * gm0;
        o.y = g1 * inv * gm1;
        *reinterpret_cast<float2*>(out + (bbase + t) * D_MODEL + d0) = o;

        #pragma unroll
        for (int j = 0; j < 5; j++) { rg[j][0] = rg[j + 1][0]; rg[j][1] = rg[j + 1][1]; }
        rg[5][0] = r60; rg[5][1] = r61;
    }
}

extern "C" void kernel_launch(void* const* d_in, const int* in_sizes, int n_in,
                              void* d_out, int out_size, void* d_ws, size_t ws_size,
                              hipStream_t stream) {
    const float* x     = (const float*)d_in[0];
    const float* sinp  = (const float*)d_in[1];
    const float* cosp  = (const float*)d_in[2];
    const float* W     = (const float*)d_in[3];
    const float* bproj = (const float*)d_in[4];
    const float* dwk   = (const float*)d_in[5];
    const float* dwb   = (const float*)d_in[6];
    const float* gamma = (const float*)d_in[7];
    float* out = (float*)d_out;

    unsigned short* xb    = (unsigned short*)d_ws;                       // 32 MB
    unsigned short* wt    = xb + (size_t)NROWS * D_MODEL;                // 4 MB
    unsigned short* projb = wt + (size_t)NPROJ * D_MODEL;                // 64 MB

    k_cvt_x<<<(NROWS * D_MODEL) / (256 * 4), 256, 0, stream>>>(x, xb);
    k_cvt_w<<<dim3(NPROJ / 32, D_MODEL / 32), 256, 0, stream>>>(W, wt);
    k_gemm<<<(NPROJ / BN) * (NROWS / BM), 512, 0, stream>>>(xb, wt, bproj, projb);
    k_post<<<B_SZ * (T_LEN / CHUNK), 512, 0, stream>>>(projb, sinp, cosp, dwk, dwb, gamma, out);
}